// Round 4
// baseline (243.518 us; speedup 1.0000x reference)
//
#include <hip/hip_runtime.h>

typedef unsigned short u16;
typedef __attribute__((ext_vector_type(8))) short bf16x8;
typedef __attribute__((ext_vector_type(4))) float f32x4;

#define S_LEN 2048
#define EMBED 512
#define HEADS 8
#define HDIM 64
#define BATCH 4
#define TOKENS (BATCH * S_LEN)

__device__ __forceinline__ u16 f2bf(float f) {
  union { float f; unsigned u; } v;
  v.f = f;
  unsigned r = v.u + 0x7fffu + ((v.u >> 16) & 1u);
  return (u16)(r >> 16);
}

__device__ __forceinline__ void gl2lds16(const void* g, void* l) {
  __builtin_amdgcn_global_load_lds(
      (const __attribute__((address_space(1))) void*)g,
      (__attribute__((address_space(3))) void*)l, 16, 0, 0);
}

// ---------------------------------------------------------------------------
// Kernel A: prep = fused gather (emb rows -> Xb bf16) + weight conversion.
// Blocks [0,2048): Xb. Blocks [2048,2560): Wq/Wo. 16B loads, 16B packed stores.
// ---------------------------------------------------------------------------
__global__ __launch_bounds__(256) void prep_kernel(
    const int* __restrict__ text, const float* __restrict__ emb,
    const float* __restrict__ in_w, const float* __restrict__ out_w,
    u16* __restrict__ Xb, u16* __restrict__ Wq, u16* __restrict__ Wo) {
  const int bid = blockIdx.x;
  const int idx = bid * 256 + threadIdx.x;
  const float* src;
  u16* dst;
  if (bid < 2048) {
    const int t = idx >> 6, c8 = (idx & 63) * 8;
    src = emb + (size_t)text[t] * EMBED + c8;
    dst = Xb + (size_t)t * EMBED + c8;
  } else {
    const int w8 = (idx - 2048 * 256) * 8;
    if (w8 < 1536 * 512) { src = in_w + w8; dst = Wq + w8; }
    else { src = out_w + (w8 - 1536 * 512); dst = Wo + (w8 - 1536 * 512); }
  }
  const float4 a = *(const float4*)src;
  const float4 b = *(const float4*)(src + 4);
  uint4 p;
  p.x = (unsigned)f2bf(a.x) | ((unsigned)f2bf(a.y) << 16);
  p.y = (unsigned)f2bf(a.z) | ((unsigned)f2bf(a.w) << 16);
  p.z = (unsigned)f2bf(b.x) | ((unsigned)f2bf(b.y) << 16);
  p.w = (unsigned)f2bf(b.z) | ((unsigned)f2bf(b.w) << 16);
  *(uint4*)dst = p;
}

// ---------------------------------------------------------------------------
// Kernel C: QKV GEMM (bf16 MFMA). 128x128 tile, BK=64, 4 waves, 4x4 MFMA grid.
// Grid (12 n-panels, 64 m-tiles): n fastest so A-tile reuse is L2-tight.
// ---------------------------------------------------------------------------
__global__ __launch_bounds__(256, 3) void qkv_mfma(
    const u16* __restrict__ Xb, const u16* __restrict__ Wq,
    const float* __restrict__ in_b,
    u16* __restrict__ qg, u16* __restrict__ kg, u16* __restrict__ vt) {
  __shared__ u16 As[128 * 64];
  __shared__ u16 Bs[128 * 64];
  const int m0 = blockIdx.y * 128, n0 = blockIdx.x * 128;
  const int tid = threadIdx.x;
  const int w = tid >> 6, l = tid & 63, quad = l >> 4, ln = l & 15;
  const int rb = (w >> 1) * 64, cb = (w & 1) * 64;

  f32x4 acc[4][4] = {};

  for (int k0 = 0; k0 < EMBED; k0 += 64) {
#pragma unroll
    for (int it = 0; it < 4; ++it) {
      const int chunk = it * 256 + tid;
      const int row = chunk >> 3, cp = chunk & 7, c = cp ^ (row & 7);
      gl2lds16(Xb + (size_t)(m0 + row) * EMBED + k0 + c * 8, &As[chunk * 8]);
      gl2lds16(Wq + (size_t)(n0 + row) * EMBED + k0 + c * 8, &Bs[chunk * 8]);
    }
    __syncthreads();
#pragma unroll
    for (int s = 0; s < 2; ++s) {
      bf16x8 af[4], bf[4];
#pragma unroll
      for (int i = 0; i < 4; ++i) {
        const int r = rb + 16 * i + ln;
        af[i] = *(const bf16x8*)&As[r * 64 + (((s << 2) + quad) ^ (r & 7)) * 8];
      }
#pragma unroll
      for (int j = 0; j < 4; ++j) {
        const int n = cb + 16 * j + ln;
        bf[j] = *(const bf16x8*)&Bs[n * 64 + (((s << 2) + quad) ^ (n & 7)) * 8];
      }
#pragma unroll
      for (int i = 0; i < 4; ++i)
#pragma unroll
        for (int j = 0; j < 4; ++j)
          acc[i][j] = __builtin_amdgcn_mfma_f32_16x16x32_bf16(af[i], bf[j], acc[i][j], 0, 0, 0);
    }
    __syncthreads();
  }

#pragma unroll
  for (int j = 0; j < 4; ++j) {
    const int n = n0 + cb + 16 * j + ln;
    const float bias = in_b[n];
    const int sec = n >> 9, f = n & 511, h = f >> 6, d = f & 63;
#pragma unroll
    for (int i = 0; i < 4; ++i) {
      if (sec == 2) {
        // v transposed: s consecutive -> pack pairs as u32
#pragma unroll
        for (int r = 0; r < 4; r += 2) {
          const int t = m0 + rb + 16 * i + quad * 4 + r;
          const int b = t >> 11, s = t & 2047;
          const unsigned p = (unsigned)f2bf(acc[i][j][r] + bias) |
                             ((unsigned)f2bf(acc[i][j][r + 1] + bias) << 16);
          *(unsigned*)&vt[((size_t)((b * HEADS + h) * HDIM + d)) * S_LEN + s] = p;
        }
      } else {
#pragma unroll
        for (int r = 0; r < 4; ++r) {
          const int t = m0 + rb + 16 * i + quad * 4 + r;
          const int b = t >> 11, s = t & 2047;
          const float val = acc[i][j][r] + bias;
          if (sec == 0)
            qg[((size_t)((b * HEADS + h) * S_LEN + s)) * HDIM + d] = f2bf(val * 0.125f);
          else
            kg[((size_t)((b * HEADS + h) * S_LEN + s)) * HDIM + d] = f2bf(val);
        }
      }
    }
  }
}

// ---------------------------------------------------------------------------
// Kernel D: banded attention, MFMA. Block = (64 query rows) x (b,h).
// All-P-at-once design: P written to its own 40KB swizzled LDS buffer after
// softmax; PV loop has no per-iteration barriers. Wave-uniform tile skipping.
// ---------------------------------------------------------------------------
__global__ __launch_bounds__(256, 2) void attn_mfma(
    const u16* __restrict__ qg, const u16* __restrict__ kg,
    const u16* __restrict__ vt, u16* __restrict__ attnb) {
  __shared__ u16 KV[320 * 64];   // 40 KB: K band [320][8 swz-chunks], then V^T [64][40 swz-chunks]
  __shared__ u16 Ps[64 * 320];   // 40 KB: P [64 rows][40 swz-chunks of 8]
  const int bh = blockIdx.y;
  const int i0 = blockIdx.x * 64;
  const int jb = i0 - 128;
  const int tid = threadIdx.x;
  const int w = tid >> 6, l = tid & 63, quad = l >> 4, ln = l & 15;

  // wave-uniform coverage of local cols c = gj - jb for this wave's 16 rows
  const int clo = (w * 16 > -jb) ? w * 16 : -jb;
  const int chiraw = w * 16 + 271, chimax = 2047 - jb;
  const int chi = chiraw < chimax ? chiraw : chimax;
  const int kt0 = clo >> 5, kt1 = chi >> 5;          // 32-col PV chunks
  const int jt0 = kt0 << 1, jt1 = (kt1 << 1) + 1;    // 16-col score tiles (kt-aligned)

  // Q A-frags (pre-scaled by 1/8 in qkv epilogue)
  const u16* qrow = qg + ((size_t)bh * S_LEN + i0 + w * 16 + ln) * HDIM;
  bf16x8 qf[2];
  qf[0] = *(const bf16x8*)(qrow + quad * 8);
  qf[1] = *(const bf16x8*)(qrow + 32 + quad * 8);

  // stage K band [320 rows][8 chunks], source-col swizzled
  const u16* kbase = kg + (size_t)bh * S_LEN * HDIM;
#pragma unroll
  for (int it = 0; it < 10; ++it) {
    const int chunk = it * 256 + tid;
    const int row = chunk >> 3, cp = chunk & 7, c = cp ^ (row & 7);
    int gj = jb + row;
    gj = gj < 0 ? 0 : (gj > S_LEN - 1 ? S_LEN - 1 : gj);
    gl2lds16(kbase + (size_t)gj * HDIM + c * 8, &KV[chunk * 8]);
  }
  __syncthreads();

  // scores (only covered tiles)
  f32x4 sc[20];
#pragma unroll
  for (int jt = 0; jt < 20; ++jt) {
    if (jt < jt0 || jt > jt1) continue;
    const int r = jt * 16 + ln;
    const bf16x8 b0 = *(const bf16x8*)&KV[r * 64 + ((quad) ^ (r & 7)) * 8];
    const bf16x8 b1 = *(const bf16x8*)&KV[r * 64 + ((4 + quad) ^ (r & 7)) * 8];
    f32x4 a = {};
    a = __builtin_amdgcn_mfma_f32_16x16x32_bf16(qf[0], b0, a, 0, 0, 0);
    a = __builtin_amdgcn_mfma_f32_16x16x32_bf16(qf[1], b1, a, 0, 0, 0);
    sc[jt] = a;
  }
  __syncthreads();  // all K reads done; KV region free

  // stage V^T band [64 d-rows][40 chunks], source-col swizzled (async)
  const u16* vbase = vt + (size_t)bh * HDIM * S_LEN;
#pragma unroll
  for (int it = 0; it < 10; ++it) {
    const int chunk = it * 256 + tid;
    const int row = chunk / 40, cp = chunk % 40, c = cp ^ (row & 7);
    int gc = jb + c * 8;
    gc = gc < 0 ? 0 : (gc > S_LEN - 8 ? S_LEN - 8 : gc);
    gl2lds16(vbase + (size_t)row * S_LEN + gc, &KV[chunk * 8]);
  }

  // mask + softmax in registers (overlaps V^T staging)
  const int gibase = i0 + w * 16 + quad * 4;
  float mrow[4] = {-1e30f, -1e30f, -1e30f, -1e30f}, lrow[4];
#pragma unroll
  for (int jt = 0; jt < 20; ++jt) {
    if (jt < jt0 || jt > jt1) continue;
    const int gj = jb + jt * 16 + ln;
#pragma unroll
    for (int r = 0; r < 4; ++r) {
      const int dij = (gibase + r) - gj;
      const bool valid = (gj >= 0) && (gj < S_LEN) && (dij <= 128) && (dij >= -128);
      const float v = valid ? sc[jt][r] : -1e30f;
      sc[jt][r] = v;
      mrow[r] = fmaxf(mrow[r], v);
    }
  }
#pragma unroll
  for (int r = 0; r < 4; ++r) {
    mrow[r] = fmaxf(mrow[r], __shfl_xor(mrow[r], 1));
    mrow[r] = fmaxf(mrow[r], __shfl_xor(mrow[r], 2));
    mrow[r] = fmaxf(mrow[r], __shfl_xor(mrow[r], 4));
    mrow[r] = fmaxf(mrow[r], __shfl_xor(mrow[r], 8));
    lrow[r] = 0.f;
  }
#pragma unroll
  for (int jt = 0; jt < 20; ++jt) {
    if (jt < jt0 || jt > jt1) continue;
#pragma unroll
    for (int r = 0; r < 4; ++r) {
      const float e = __expf(sc[jt][r] - mrow[r]);
      sc[jt][r] = e;
      lrow[r] += e;
    }
  }
#pragma unroll
  for (int r = 0; r < 4; ++r) {
    lrow[r] += __shfl_xor(lrow[r], 1);
    lrow[r] += __shfl_xor(lrow[r], 2);
    lrow[r] += __shfl_xor(lrow[r], 4);
    lrow[r] += __shfl_xor(lrow[r], 8);
    lrow[r] = 1.0f / lrow[r];
  }

  // write P (normalized, bf16) into Ps: row = w*16 + quad*4 + r, col c = jt*16+ln
  // chunk = c>>3, swizzled by row&7 within 8-chunk groups
#pragma unroll
  for (int jt = 0; jt < 20; ++jt) {
    if (jt < jt0 || jt > jt1) continue;
    const int cchunk = jt * 2 + (ln >> 3);
#pragma unroll
    for (int r = 0; r < 4; ++r) {
      const int m = quad * 4 + r;
      const int swz = cchunk ^ (m & 7);
      Ps[(w * 16 + m) * 320 + swz * 8 + (ln & 7)] = f2bf(sc[jt][r] * lrow[r]);
    }
  }
  __syncthreads();  // V^T staged AND P writes drained (lgkm+vm at barrier)

  // PV: clean loop, no barriers. pa row = w*16+ln (written by this wave).
  f32x4 oacc[4] = {};
  const int prow = w * 16 + ln;
#pragma unroll
  for (int kt = 0; kt < 10; ++kt) {
    if (kt < kt0 || kt > kt1) continue;
    const int c = kt * 4 + quad;
    const bf16x8 pa = *(const bf16x8*)&Ps[prow * 320 + (c ^ (ln & 7)) * 8];
#pragma unroll
    for (int dt = 0; dt < 4; ++dt) {
      const int d = dt * 16 + ln;
      const bf16x8 vb = *(const bf16x8*)&KV[d * 320 + (c ^ (d & 7)) * 8];
      oacc[dt] = __builtin_amdgcn_mfma_f32_16x16x32_bf16(pa, vb, oacc[dt], 0, 0, 0);
    }
  }

  // write O (bf16) to attn [B][S][512]
  const int b = bh >> 3, h = bh & 7;
#pragma unroll
  for (int dt = 0; dt < 4; ++dt) {
    const int d = h * HDIM + dt * 16 + ln;
#pragma unroll
    for (int r = 0; r < 4; ++r) {
      const int gi = i0 + w * 16 + quad * 4 + r;
      attnb[((size_t)(b * S_LEN + gi)) * EMBED + d] = f2bf(oacc[dt][r]);
    }
  }
}

// ---------------------------------------------------------------------------
// Kernel E: out-projection GEMM (bf16 MFMA) + fused column max.
// Grid (4 n-panels, 64 m-tiles): n fastest for A-tile L2 reuse.
// ---------------------------------------------------------------------------
__global__ __launch_bounds__(256, 3) void outproj_mfma(
    const u16* __restrict__ attnb, const u16* __restrict__ Wo,
    const float* __restrict__ out_b, float* __restrict__ pmax) {
  __shared__ u16 As[128 * 64];
  __shared__ u16 Bs[128 * 64];
  __shared__ float red[4][64];
  const int m0 = blockIdx.y * 128, n0 = blockIdx.x * 128;
  const int tid = threadIdx.x;
  const int w = tid >> 6, l = tid & 63, quad = l >> 4, ln = l & 15;
  const int rb = (w >> 1) * 64, cb = (w & 1) * 64;

  f32x4 acc[4][4] = {};

  for (int k0 = 0; k0 < EMBED; k0 += 64) {
#pragma unroll
    for (int it = 0; it < 4; ++it) {
      const int chunk = it * 256 + tid;
      const int row = chunk >> 3, cp = chunk & 7, c = cp ^ (row & 7);
      gl2lds16(attnb + (size_t)(m0 + row) * EMBED + k0 + c * 8, &As[chunk * 8]);
      gl2lds16(Wo + (size_t)(n0 + row) * EMBED + k0 + c * 8, &Bs[chunk * 8]);
    }
    __syncthreads();
#pragma unroll
    for (int s = 0; s < 2; ++s) {
      bf16x8 af[4], bf[4];
#pragma unroll
      for (int i = 0; i < 4; ++i) {
        const int r = rb + 16 * i + ln;
        af[i] = *(const bf16x8*)&As[r * 64 + (((s << 2) + quad) ^ (r & 7)) * 8];
      }
#pragma unroll
      for (int j = 0; j < 4; ++j) {
        const int n = cb + 16 * j + ln;
        bf[j] = *(const bf16x8*)&Bs[n * 64 + (((s << 2) + quad) ^ (n & 7)) * 8];
      }
#pragma unroll
      for (int i = 0; i < 4; ++i)
#pragma unroll
        for (int j = 0; j < 4; ++j)
          acc[i][j] = __builtin_amdgcn_mfma_f32_16x16x32_bf16(af[i], bf[j], acc[i][j], 0, 0, 0);
    }
    __syncthreads();
  }

  float cm[4];
#pragma unroll
  for (int j = 0; j < 4; ++j) {
    float m = -1e30f;
#pragma unroll
    for (int i = 0; i < 4; ++i)
#pragma unroll
      for (int r = 0; r < 4; ++r) m = fmaxf(m, acc[i][j][r]);
    m = fmaxf(m, __shfl_xor(m, 16));
    m = fmaxf(m, __shfl_xor(m, 32));
    cm[j] = m;
  }
  if (l < 16) {
#pragma unroll
    for (int j = 0; j < 4; ++j) red[w][ln + 16 * j] = cm[j];
  }
  __syncthreads();
  if (tid < 128) {
    const int ch = tid >> 6, cw = tid & 63;
    const float m = fmaxf(red[ch][cw], red[ch + 2][cw]);
    const int n = n0 + ch * 64 + cw;
    const int b = m0 >> 11, stile = (m0 >> 7) & 15;
    pmax[(size_t)(b * 16 + stile) * EMBED + n] = m + out_b[n];
  }
}

// ---------------------------------------------------------------------------
// Kernel F1: ctx max-reduce + MLP layer1 slice. Grid 32 = (b<<3)|chunk.
// ---------------------------------------------------------------------------
__global__ __launch_bounds__(256) void mlp_ctx_l1(
    const float* __restrict__ pmax, const float* __restrict__ w1,
    const float* __restrict__ b1, float* __restrict__ h1g) {
  __shared__ float ctx[512];
  const int b = blockIdx.x >> 3, chunk = blockIdx.x & 7;
  const int tid = threadIdx.x;

  for (int e = tid; e < 512; e += 256) {
    float m = -1e30f;
#pragma unroll
    for (int t = 0; t < 16; ++t) m = fmaxf(m, pmax[(size_t)(b * 16 + t) * 512 + e]);
    ctx[e] = m;
  }
  __syncthreads();

  const int o = chunk * 64 + (tid >> 2), kq = tid & 3;
  float acc = 0.f;
  const float* wr = w1 + (size_t)o * 512 + kq * 128;
  const float* xr = ctx + kq * 128;
  for (int k = 0; k < 128; k += 4) {
    const float4 wv = *(const float4*)(wr + k);
    const float4 xv = *(const float4*)(xr + k);
    acc += wv.x * xv.x + wv.y * xv.y + wv.z * xv.z + wv.w * xv.w;
  }
  acc += __shfl_xor(acc, 1);
  acc += __shfl_xor(acc, 2);
  if (kq == 0) {
    const float a = acc + b1[o];
    h1g[b * 512 + o] = a > 0.f ? a : 0.01f * a;
  }
}

// ---------------------------------------------------------------------------
// Kernel F2: MLP layer2 slice. Grid 16 = (b<<2)|chunk.
// ---------------------------------------------------------------------------
__global__ __launch_bounds__(256) void mlp_l2(
    const float* __restrict__ h1g, const float* __restrict__ w2,
    const float* __restrict__ b2, float* __restrict__ h2g) {
  __shared__ float xb[512];
  const int b = blockIdx.x >> 2, chunk = blockIdx.x & 3;
  const int tid = threadIdx.x;
  for (int e = tid; e < 512; e += 256) xb[e] = h1g[b * 512 + e];
  __syncthreads();

  const int o = chunk * 64 + (tid >> 2), kq = tid & 3;
  float acc = 0.f;
  const float* wr = w2 + (size_t)o * 512 + kq * 128;
  const float* xr = xb + kq * 128;
  for (int k = 0; k < 128; k += 4) {
    const float4 wv = *(const float4*)(wr + k);
    const float4 xv = *(const float4*)(xr + k);
    acc += wv.x * xv.x + wv.y * xv.y + wv.z * xv.z + wv.w * xv.w;
  }
  acc += __shfl_xor(acc, 1);
  acc += __shfl_xor(acc, 2);
  if (kq == 0) {
    const float a = acc + b2[o];
    h2g[b * 256 + o] = a > 0.f ? a : 0.01f * a;
  }
}

// ---------------------------------------------------------------------------
// Kernel F3: MLP layer3 + layer4. Grid 4.
// ---------------------------------------------------------------------------
__global__ __launch_bounds__(256) void mlp_l34(
    const float* __restrict__ h2g,
    const float* __restrict__ w3, const float* __restrict__ b3,
    const float* __restrict__ w4, const float* __restrict__ b4,
    float* __restrict__ out) {
  __shared__ float xb[256], h3[128];
  const int b = blockIdx.x, tid = threadIdx.x;
  if (tid < 256) xb[tid] = h2g[b * 256 + tid];
  __syncthreads();

  {
    const int o = tid >> 1, kh = tid & 1;
    float acc = 0.f;
    const float* wr = w3 + (size_t)o * 256 + kh * 128;
    const float* xr = xb + kh * 128;
    for (int k = 0; k < 128; k += 4) {
      const float4 wv = *(const float4*)(wr + k);
      const float4 xv = *(const float4*)(xr + k);
      acc += wv.x * xv.x + wv.y * xv.y + wv.z * xv.z + wv.w * xv.w;
    }
    acc += __shfl_xor(acc, 1);
    if (kh == 0) { const float a = acc + b3[o]; h3[o] = a > 0.f ? a : 0.01f * a; }
  }
  __syncthreads();

  if (tid < 160) {
    const int o = tid >> 3, ks = tid & 7;
    const float* wr = w4 + (size_t)o * 128 + ks * 16;
    const float* xr = h3 + ks * 16;
    float acc = 0.f;
    for (int k = 0; k < 16; k += 4) {
      const float4 wv = *(const float4*)(wr + k);
      const float4 xv = *(const float4*)(xr + k);
      acc += wv.x * xv.x + wv.y * xv.y + wv.z * xv.z + wv.w * xv.w;
    }
    acc += __shfl_xor(acc, 1);
    acc += __shfl_xor(acc, 2);
    acc += __shfl_xor(acc, 4);
    if (ks == 0) out[b * 20 + o] = acc + b4[o];
  }
}

// ---------------------------------------------------------------------------
extern "C" void kernel_launch(void* const* d_in, const int* in_sizes, int n_in,
                              void* d_out, int out_size, void* d_ws, size_t ws_size,
                              hipStream_t stream) {
  (void)in_sizes; (void)n_in; (void)out_size; (void)ws_size;
  const int*   text  = (const int*)d_in[0];
  const float* emb   = (const float*)d_in[1];
  const float* in_w  = (const float*)d_in[2];
  const float* in_b  = (const float*)d_in[3];
  const float* out_w = (const float*)d_in[4];
  const float* out_b = (const float*)d_in[5];
  const float* w1 = (const float*)d_in[6];
  const float* b1 = (const float*)d_in[7];
  const float* w2 = (const float*)d_in[8];
  const float* b2 = (const float*)d_in[9];
  const float* w3 = (const float*)d_in[10];
  const float* b3 = (const float*)d_in[11];
  const float* w4 = (const float*)d_in[12];
  const float* b4 = (const float*)d_in[13];

  char* ws = (char*)d_ws;
  u16* Xb   = (u16*)(ws);                       // 8192*512*2   = 8388608
  u16* Wq   = (u16*)(ws + 8388608);             // 1536*512*2   = 1572864
  u16* Wo   = (u16*)(ws + 9961472);             // 512*512*2    = 524288
  u16* qg   = (u16*)(ws + 10485760);
  u16* kg   = (u16*)(ws + 18874368);
  u16* vt   = (u16*)(ws + 27262976);
  u16* attn = (u16*)(ws + 35651584);
  float* pmax = (float*)(ws + 44040192);        // 4*16*512*4   = 131072
  float* h1g  = (float*)(ws + 44171264);
  float* h2g  = (float*)(ws + 44179456);

  prep_kernel<<<2560, 256, 0, stream>>>(text, emb, in_w, out_w, Xb, Wq, Wo);
  qkv_mfma<<<dim3(12, 64), 256, 0, stream>>>(Xb, Wq, in_b, qg, kg, vt);
  attn_mfma<<<dim3(32, 32), 256, 0, stream>>>(qg, kg, vt, attn);
  outproj_mfma<<<dim3(4, 64), 256, 0, stream>>>(attn, Wo, out_b, pmax);
  mlp_ctx_l1<<<32, 256, 0, stream>>>(pmax, w1, b1, h1g);
  mlp_l2<<<16, 256, 0, stream>>>(h1g, w2, b2, h2g);
  mlp_l34<<<4, 256, 0, stream>>>(h2g, w3, b3, w4, b4, (float*)d_out);
}

// Round 5
// 242.687 us; speedup vs baseline: 1.0034x; 1.0034x over previous
//
#include <hip/hip_runtime.h>

typedef unsigned short u16;
typedef __attribute__((ext_vector_type(8))) short bf16x8;
typedef __attribute__((ext_vector_type(4))) float f32x4;

#define S_LEN 2048
#define EMBED 512
#define HEADS 8
#define HDIM 64
#define BATCH 4
#define TOKENS (BATCH * S_LEN)

__device__ __forceinline__ u16 f2bf(float f) {
  union { float f; unsigned u; } v;
  v.f = f;
  unsigned r = v.u + 0x7fffu + ((v.u >> 16) & 1u);
  return (u16)(r >> 16);
}

__device__ __forceinline__ void gl2lds16(const void* g, void* l) {
  __builtin_amdgcn_global_load_lds(
      (const __attribute__((address_space(1))) void*)g,
      (__attribute__((address_space(3))) void*)l, 16, 0, 0);
}

// ---------------------------------------------------------------------------
// Kernel A: prep = fused gather (emb rows -> Xb bf16) + weight conversion.
// ---------------------------------------------------------------------------
__global__ __launch_bounds__(256) void prep_kernel(
    const int* __restrict__ text, const float* __restrict__ emb,
    const float* __restrict__ in_w, const float* __restrict__ out_w,
    u16* __restrict__ Xb, u16* __restrict__ Wq, u16* __restrict__ Wo) {
  const int bid = blockIdx.x;
  const int idx = bid * 256 + threadIdx.x;
  const float* src;
  u16* dst;
  if (bid < 2048) {
    const int t = idx >> 6, c8 = (idx & 63) * 8;
    src = emb + (size_t)text[t] * EMBED + c8;
    dst = Xb + (size_t)t * EMBED + c8;
  } else {
    const int w8 = (idx - 2048 * 256) * 8;
    if (w8 < 1536 * 512) { src = in_w + w8; dst = Wq + w8; }
    else { src = out_w + (w8 - 1536 * 512); dst = Wo + (w8 - 1536 * 512); }
  }
  const float4 a = *(const float4*)src;
  const float4 b = *(const float4*)(src + 4);
  uint4 p;
  p.x = (unsigned)f2bf(a.x) | ((unsigned)f2bf(a.y) << 16);
  p.y = (unsigned)f2bf(a.z) | ((unsigned)f2bf(a.w) << 16);
  p.z = (unsigned)f2bf(b.x) | ((unsigned)f2bf(b.y) << 16);
  p.w = (unsigned)f2bf(b.z) | ((unsigned)f2bf(b.w) << 16);
  *(uint4*)dst = p;
}

// ---------------------------------------------------------------------------
// Kernel C: QKV GEMM (bf16 MFMA). 128x128 tile, BK=64, 4 waves, 4x4 MFMA grid.
// q/k panels (sec<2): computed TRANSPOSED (W = A-operand) so the 4 consecutive
// C-layout rows are 4 consecutive d -> 8B packed coalesced stores.
// v panels: original orientation (s-direction pair packing into vt).
// ---------------------------------------------------------------------------
__global__ __launch_bounds__(256, 3) void qkv_mfma(
    const u16* __restrict__ Xb, const u16* __restrict__ Wq,
    const float* __restrict__ in_b,
    u16* __restrict__ qg, u16* __restrict__ kg, u16* __restrict__ vt) {
  __shared__ u16 As[128 * 64];   // X tile (rows = t)
  __shared__ u16 Bs[128 * 64];   // W tile (rows = n)
  const int m0 = blockIdx.y * 128, n0 = blockIdx.x * 128;
  const int sec = n0 >> 9;       // 0:q 1:k 2:v, uniform per block
  const int tid = threadIdx.x;
  const int w = tid >> 6, l = tid & 63, quad = l >> 4, ln = l & 15;
  const int rb = (w >> 1) * 64, cb = (w & 1) * 64;

  const u16* Ms = (sec < 2) ? Bs : As;  // matrix supplying MFMA M-dim
  const u16* Ns = (sec < 2) ? As : Bs;

  f32x4 acc[4][4] = {};

  for (int k0 = 0; k0 < EMBED; k0 += 64) {
#pragma unroll
    for (int it = 0; it < 4; ++it) {
      const int chunk = it * 256 + tid;
      const int row = chunk >> 3, cp = chunk & 7, c = cp ^ (row & 7);
      gl2lds16(Xb + (size_t)(m0 + row) * EMBED + k0 + c * 8, &As[chunk * 8]);
      gl2lds16(Wq + (size_t)(n0 + row) * EMBED + k0 + c * 8, &Bs[chunk * 8]);
    }
    __syncthreads();
#pragma unroll
    for (int s = 0; s < 2; ++s) {
      bf16x8 af[4], bf[4];
#pragma unroll
      for (int i = 0; i < 4; ++i) {
        const int r = rb + 16 * i + ln;
        af[i] = *(const bf16x8*)&Ms[r * 64 + (((s << 2) + quad) ^ (r & 7)) * 8];
      }
#pragma unroll
      for (int j = 0; j < 4; ++j) {
        const int n = cb + 16 * j + ln;
        bf[j] = *(const bf16x8*)&Ns[n * 64 + (((s << 2) + quad) ^ (n & 7)) * 8];
      }
#pragma unroll
      for (int i = 0; i < 4; ++i)
#pragma unroll
        for (int j = 0; j < 4; ++j)
          acc[i][j] = __builtin_amdgcn_mfma_f32_16x16x32_bf16(af[i], bf[j], acc[i][j], 0, 0, 0);
    }
    __syncthreads();
  }

  if (sec < 2) {
    // transposed: M-dim = n (4 consecutive d per lane), N-dim = t
    u16* dstg = (sec == 0) ? qg : kg;
    const float scale = (sec == 0) ? 0.125f : 1.0f;
#pragma unroll
    for (int i = 0; i < 4; ++i) {
      const int nbase = n0 + rb + 16 * i + quad * 4;
      const int f = nbase & 511, h = f >> 6, d = f & 63;
      const float4 bias = *(const float4*)(in_b + nbase);
#pragma unroll
      for (int j = 0; j < 4; ++j) {
        const int t = m0 + cb + 16 * j + ln;
        const int b = t >> 11, s = t & 2047;
        uint2 p;
        p.x = (unsigned)f2bf((acc[i][j][0] + bias.x) * scale) |
              ((unsigned)f2bf((acc[i][j][1] + bias.y) * scale) << 16);
        p.y = (unsigned)f2bf((acc[i][j][2] + bias.z) * scale) |
              ((unsigned)f2bf((acc[i][j][3] + bias.w) * scale) << 16);
        *(uint2*)&dstg[((size_t)((b * HEADS + h) * S_LEN + s)) * HDIM + d] = p;
      }
    }
  } else {
    // v: original orientation, pack s-pairs into vt [B][H][64][S]
#pragma unroll
    for (int j = 0; j < 4; ++j) {
      const int n = n0 + cb + 16 * j + ln;
      const float bias = in_b[n];
      const int f = n & 511, h = f >> 6, d = f & 63;
#pragma unroll
      for (int i = 0; i < 4; ++i) {
#pragma unroll
        for (int r = 0; r < 4; r += 2) {
          const int t = m0 + rb + 16 * i + quad * 4 + r;
          const int b = t >> 11, s = t & 2047;
          const unsigned p = (unsigned)f2bf(acc[i][j][r] + bias) |
                             ((unsigned)f2bf(acc[i][j][r + 1] + bias) << 16);
          *(unsigned*)&vt[((size_t)((b * HEADS + h) * HDIM + d)) * S_LEN + s] = p;
        }
      }
    }
  }
}

// ---------------------------------------------------------------------------
// Kernel D: banded attention, MFMA. Block = (64 query rows) x (b,h).
// ---------------------------------------------------------------------------
__global__ __launch_bounds__(256, 2) void attn_mfma(
    const u16* __restrict__ qg, const u16* __restrict__ kg,
    const u16* __restrict__ vt, u16* __restrict__ attnb) {
  __shared__ u16 KV[320 * 64];   // 40 KB
  __shared__ u16 Ps[64 * 320];   // 40 KB
  const int bh = blockIdx.y;
  const int i0 = blockIdx.x * 64;
  const int jb = i0 - 128;
  const int tid = threadIdx.x;
  const int w = tid >> 6, l = tid & 63, quad = l >> 4, ln = l & 15;

  const int clo = (w * 16 > -jb) ? w * 16 : -jb;
  const int chiraw = w * 16 + 271, chimax = 2047 - jb;
  const int chi = chiraw < chimax ? chiraw : chimax;
  const int kt0 = clo >> 5, kt1 = chi >> 5;
  const int jt0 = kt0 << 1, jt1 = (kt1 << 1) + 1;

  const u16* qrow = qg + ((size_t)bh * S_LEN + i0 + w * 16 + ln) * HDIM;
  bf16x8 qf[2];
  qf[0] = *(const bf16x8*)(qrow + quad * 8);
  qf[1] = *(const bf16x8*)(qrow + 32 + quad * 8);

  const u16* kbase = kg + (size_t)bh * S_LEN * HDIM;
#pragma unroll
  for (int it = 0; it < 10; ++it) {
    const int chunk = it * 256 + tid;
    const int row = chunk >> 3, cp = chunk & 7, c = cp ^ (row & 7);
    int gj = jb + row;
    gj = gj < 0 ? 0 : (gj > S_LEN - 1 ? S_LEN - 1 : gj);
    gl2lds16(kbase + (size_t)gj * HDIM + c * 8, &KV[chunk * 8]);
  }
  __syncthreads();

  f32x4 sc[20];
#pragma unroll
  for (int jt = 0; jt < 20; ++jt) {
    if (jt < jt0 || jt > jt1) continue;
    const int r = jt * 16 + ln;
    const bf16x8 b0 = *(const bf16x8*)&KV[r * 64 + ((quad) ^ (r & 7)) * 8];
    const bf16x8 b1 = *(const bf16x8*)&KV[r * 64 + ((4 + quad) ^ (r & 7)) * 8];
    f32x4 a = {};
    a = __builtin_amdgcn_mfma_f32_16x16x32_bf16(qf[0], b0, a, 0, 0, 0);
    a = __builtin_amdgcn_mfma_f32_16x16x32_bf16(qf[1], b1, a, 0, 0, 0);
    sc[jt] = a;
  }
  __syncthreads();

  const u16* vbase = vt + (size_t)bh * HDIM * S_LEN;
#pragma unroll
  for (int it = 0; it < 10; ++it) {
    const int chunk = it * 256 + tid;
    const int row = chunk / 40, cp = chunk % 40, c = cp ^ (row & 7);
    int gc = jb + c * 8;
    gc = gc < 0 ? 0 : (gc > S_LEN - 8 ? S_LEN - 8 : gc);
    gl2lds16(vbase + (size_t)row * S_LEN + gc, &KV[chunk * 8]);
  }

  const int gibase = i0 + w * 16 + quad * 4;
  float mrow[4] = {-1e30f, -1e30f, -1e30f, -1e30f}, lrow[4];
#pragma unroll
  for (int jt = 0; jt < 20; ++jt) {
    if (jt < jt0 || jt > jt1) continue;
    const int gj = jb + jt * 16 + ln;
#pragma unroll
    for (int r = 0; r < 4; ++r) {
      const int dij = (gibase + r) - gj;
      const bool valid = (gj >= 0) && (gj < S_LEN) && (dij <= 128) && (dij >= -128);
      const float v = valid ? sc[jt][r] : -1e30f;
      sc[jt][r] = v;
      mrow[r] = fmaxf(mrow[r], v);
    }
  }
#pragma unroll
  for (int r = 0; r < 4; ++r) {
    mrow[r] = fmaxf(mrow[r], __shfl_xor(mrow[r], 1));
    mrow[r] = fmaxf(mrow[r], __shfl_xor(mrow[r], 2));
    mrow[r] = fmaxf(mrow[r], __shfl_xor(mrow[r], 4));
    mrow[r] = fmaxf(mrow[r], __shfl_xor(mrow[r], 8));
    lrow[r] = 0.f;
  }
#pragma unroll
  for (int jt = 0; jt < 20; ++jt) {
    if (jt < jt0 || jt > jt1) continue;
#pragma unroll
    for (int r = 0; r < 4; ++r) {
      const float e = __expf(sc[jt][r] - mrow[r]);
      sc[jt][r] = e;
      lrow[r] += e;
    }
  }
#pragma unroll
  for (int r = 0; r < 4; ++r) {
    lrow[r] += __shfl_xor(lrow[r], 1);
    lrow[r] += __shfl_xor(lrow[r], 2);
    lrow[r] += __shfl_xor(lrow[r], 4);
    lrow[r] += __shfl_xor(lrow[r], 8);
    lrow[r] = 1.0f / lrow[r];
  }

#pragma unroll
  for (int jt = 0; jt < 20; ++jt) {
    if (jt < jt0 || jt > jt1) continue;
    const int cchunk = jt * 2 + (ln >> 3);
#pragma unroll
    for (int r = 0; r < 4; ++r) {
      const int m = quad * 4 + r;
      const int swz = cchunk ^ (m & 7);
      Ps[(w * 16 + m) * 320 + swz * 8 + (ln & 7)] = f2bf(sc[jt][r] * lrow[r]);
    }
  }
  __syncthreads();

  f32x4 oacc[4] = {};
  const int prow = w * 16 + ln;
#pragma unroll
  for (int kt = 0; kt < 10; ++kt) {
    if (kt < kt0 || kt > kt1) continue;
    const int c = kt * 4 + quad;
    const bf16x8 pa = *(const bf16x8*)&Ps[prow * 320 + (c ^ (ln & 7)) * 8];
#pragma unroll
    for (int dt = 0; dt < 4; ++dt) {
      const int d = dt * 16 + ln;
      const bf16x8 vb = *(const bf16x8*)&KV[d * 320 + (c ^ (d & 7)) * 8];
      oacc[dt] = __builtin_amdgcn_mfma_f32_16x16x32_bf16(pa, vb, oacc[dt], 0, 0, 0);
    }
  }

  const int b = bh >> 3, h = bh & 7;
#pragma unroll
  for (int dt = 0; dt < 4; ++dt) {
    const int d = h * HDIM + dt * 16 + ln;
#pragma unroll
    for (int r = 0; r < 4; ++r) {
      const int gi = i0 + w * 16 + quad * 4 + r;
      attnb[((size_t)(b * S_LEN + gi)) * EMBED + d] = f2bf(oacc[dt][r]);
    }
  }
}

// ---------------------------------------------------------------------------
// Kernel E: out-projection GEMM (bf16 MFMA) + fused column max.
// 128(m)x64(n) tiles, grid (8 n-panels, 64 m-tiles) = 512 blocks -> 2/CU.
// ---------------------------------------------------------------------------
__global__ __launch_bounds__(256, 2) void outproj_mfma(
    const u16* __restrict__ attnb, const u16* __restrict__ Wo,
    const float* __restrict__ out_b, float* __restrict__ pmax) {
  __shared__ u16 As[128 * 64];  // attn rows
  __shared__ u16 Bs[64 * 64];   // Wo rows
  __shared__ float red[4][32];
  const int m0 = blockIdx.y * 128, n0 = blockIdx.x * 64;
  const int tid = threadIdx.x;
  const int w = tid >> 6, l = tid & 63, quad = l >> 4, ln = l & 15;
  const int rb = (w >> 1) * 64, cb = (w & 1) * 32;

  f32x4 acc[4][2] = {};

  for (int k0 = 0; k0 < EMBED; k0 += 64) {
#pragma unroll
    for (int it = 0; it < 4; ++it) {
      const int chunk = it * 256 + tid;
      const int row = chunk >> 3, cp = chunk & 7, c = cp ^ (row & 7);
      gl2lds16(attnb + (size_t)(m0 + row) * EMBED + k0 + c * 8, &As[chunk * 8]);
    }
#pragma unroll
    for (int it = 0; it < 2; ++it) {
      const int chunk = it * 256 + tid;
      const int row = chunk >> 3, cp = chunk & 7, c = cp ^ (row & 7);
      gl2lds16(Wo + (size_t)(n0 + row) * EMBED + k0 + c * 8, &Bs[chunk * 8]);
    }
    __syncthreads();
#pragma unroll
    for (int s = 0; s < 2; ++s) {
      bf16x8 af[4], bf[2];
#pragma unroll
      for (int i = 0; i < 4; ++i) {
        const int r = rb + 16 * i + ln;
        af[i] = *(const bf16x8*)&As[r * 64 + (((s << 2) + quad) ^ (r & 7)) * 8];
      }
#pragma unroll
      for (int j = 0; j < 2; ++j) {
        const int n = cb + 16 * j + ln;
        bf[j] = *(const bf16x8*)&Bs[n * 64 + (((s << 2) + quad) ^ (n & 7)) * 8];
      }
#pragma unroll
      for (int i = 0; i < 4; ++i)
#pragma unroll
        for (int j = 0; j < 2; ++j)
          acc[i][j] = __builtin_amdgcn_mfma_f32_16x16x32_bf16(af[i], bf[j], acc[i][j], 0, 0, 0);
    }
    __syncthreads();
  }

  float cm[2];
#pragma unroll
  for (int j = 0; j < 2; ++j) {
    float m = -1e30f;
#pragma unroll
    for (int i = 0; i < 4; ++i)
#pragma unroll
      for (int r = 0; r < 4; ++r) m = fmaxf(m, acc[i][j][r]);
    m = fmaxf(m, __shfl_xor(m, 16));
    m = fmaxf(m, __shfl_xor(m, 32));
    cm[j] = m;
  }
  if (l < 16) {
#pragma unroll
    for (int j = 0; j < 2; ++j) red[w][16 * j + ln] = cm[j];
  }
  __syncthreads();
  if (tid < 64) {
    const int c = tid;
    const float m = fmaxf(red[c >> 5][c & 31], red[(c >> 5) + 2][c & 31]);
    const int n = n0 + c;
    const int b = m0 >> 11, stile = (m0 >> 7) & 15;
    pmax[(size_t)(b * 16 + stile) * EMBED + n] = m + out_b[n];
  }
}

// ---------------------------------------------------------------------------
// Kernel F1: ctx max-reduce + MLP layer1 slice. Grid 32.
// ---------------------------------------------------------------------------
__global__ __launch_bounds__(256) void mlp_ctx_l1(
    const float* __restrict__ pmax, const float* __restrict__ w1,
    const float* __restrict__ b1, float* __restrict__ h1g) {
  __shared__ float ctx[512];
  const int b = blockIdx.x >> 3, chunk = blockIdx.x & 7;
  const int tid = threadIdx.x;

  for (int e = tid; e < 512; e += 256) {
    float m = -1e30f;
#pragma unroll
    for (int t = 0; t < 16; ++t) m = fmaxf(m, pmax[(size_t)(b * 16 + t) * 512 + e]);
    ctx[e] = m;
  }
  __syncthreads();

  const int o = chunk * 64 + (tid >> 2), kq = tid & 3;
  float acc = 0.f;
  const float* wr = w1 + (size_t)o * 512 + kq * 128;
  const float* xr = ctx + kq * 128;
  for (int k = 0; k < 128; k += 4) {
    const float4 wv = *(const float4*)(wr + k);
    const float4 xv = *(const float4*)(xr + k);
    acc += wv.x * xv.x + wv.y * xv.y + wv.z * xv.z + wv.w * xv.w;
  }
  acc += __shfl_xor(acc, 1);
  acc += __shfl_xor(acc, 2);
  if (kq == 0) {
    const float a = acc + b1[o];
    h1g[b * 512 + o] = a > 0.f ? a : 0.01f * a;
  }
}

// ---------------------------------------------------------------------------
// Kernel F2: MLP layer2 slice. Grid 16.
// ---------------------------------------------------------------------------
__global__ __launch_bounds__(256) void mlp_l2(
    const float* __restrict__ h1g, const float* __restrict__ w2,
    const float* __restrict__ b2, float* __restrict__ h2g) {
  __shared__ float xb[512];
  const int b = blockIdx.x >> 2, chunk = blockIdx.x & 3;
  const int tid = threadIdx.x;
  for (int e = tid; e < 512; e += 256) xb[e] = h1g[b * 512 + e];
  __syncthreads();

  const int o = chunk * 64 + (tid >> 2), kq = tid & 3;
  float acc = 0.f;
  const float* wr = w2 + (size_t)o * 512 + kq * 128;
  const float* xr = xb + kq * 128;
  for (int k = 0; k < 128; k += 4) {
    const float4 wv = *(const float4*)(wr + k);
    const float4 xv = *(const float4*)(xr + k);
    acc += wv.x * xv.x + wv.y * xv.y + wv.z * xv.z + wv.w * xv.w;
  }
  acc += __shfl_xor(acc, 1);
  acc += __shfl_xor(acc, 2);
  if (kq == 0) {
    const float a = acc + b2[o];
    h2g[b * 256 + o] = a > 0.f ? a : 0.01f * a;
  }
}

// ---------------------------------------------------------------------------
// Kernel F3: MLP layer3 + layer4. Grid 4.
// ---------------------------------------------------------------------------
__global__ __launch_bounds__(256) void mlp_l34(
    const float* __restrict__ h2g,
    const float* __restrict__ w3, const float* __restrict__ b3,
    const float* __restrict__ w4, const float* __restrict__ b4,
    float* __restrict__ out) {
  __shared__ float xb[256], h3[128];
  const int b = blockIdx.x, tid = threadIdx.x;
  if (tid < 256) xb[tid] = h2g[b * 256 + tid];
  __syncthreads();

  {
    const int o = tid >> 1, kh = tid & 1;
    float acc = 0.f;
    const float* wr = w3 + (size_t)o * 256 + kh * 128;
    const float* xr = xb + kh * 128;
    for (int k = 0; k < 128; k += 4) {
      const float4 wv = *(const float4*)(wr + k);
      const float4 xv = *(const float4*)(xr + k);
      acc += wv.x * xv.x + wv.y * xv.y + wv.z * xv.z + wv.w * xv.w;
    }
    acc += __shfl_xor(acc, 1);
    if (kh == 0) { const float a = acc + b3[o]; h3[o] = a > 0.f ? a : 0.01f * a; }
  }
  __syncthreads();

  if (tid < 160) {
    const int o = tid >> 3, ks = tid & 7;
    const float* wr = w4 + (size_t)o * 128 + ks * 16;
    const float* xr = h3 + ks * 16;
    float acc = 0.f;
    for (int k = 0; k < 16; k += 4) {
      const float4 wv = *(const float4*)(wr + k);
      const float4 xv = *(const float4*)(xr + k);
      acc += wv.x * xv.x + wv.y * xv.y + wv.z * xv.z + wv.w * xv.w;
    }
    acc += __shfl_xor(acc, 1);
    acc += __shfl_xor(acc, 2);
    acc += __shfl_xor(acc, 4);
    if (ks == 0) out[b * 20 + o] = acc + b4[o];
  }
}

// ---------------------------------------------------------------------------
extern "C" void kernel_launch(void* const* d_in, const int* in_sizes, int n_in,
                              void* d_out, int out_size, void* d_ws, size_t ws_size,
                              hipStream_t stream) {
  (void)in_sizes; (void)n_in; (void)out_size; (void)ws_size;
  const int*   text  = (const int*)d_in[0];
  const float* emb   = (const float*)d_in[1];
  const float* in_w  = (const float*)d_in[2];
  const float* in_b  = (const float*)d_in[3];
  const float* out_w = (const float*)d_in[4];
  const float* out_b = (const float*)d_in[5];
  const float* w1 = (const float*)d_in[6];
  const float* b1 = (const float*)d_in[7];
  const float* w2 = (const float*)d_in[8];
  const float* b2 = (const float*)d_in[9];
  const float* w3 = (const float*)d_in[10];
  const float* b3 = (const float*)d_in[11];
  const float* w4 = (const float*)d_in[12];
  const float* b4 = (const float*)d_in[13];

  char* ws = (char*)d_ws;
  u16* Xb   = (u16*)(ws);
  u16* Wq   = (u16*)(ws + 8388608);
  u16* Wo   = (u16*)(ws + 9961472);
  u16* qg   = (u16*)(ws + 10485760);
  u16* kg   = (u16*)(ws + 18874368);
  u16* vt   = (u16*)(ws + 27262976);
  u16* attn = (u16*)(ws + 35651584);
  float* pmax = (float*)(ws + 44040192);
  float* h1g  = (float*)(ws + 44171264);
  float* h2g  = (float*)(ws + 44179456);

  prep_kernel<<<2560, 256, 0, stream>>>(text, emb, in_w, out_w, Xb, Wq, Wo);
  qkv_mfma<<<dim3(12, 64), 256, 0, stream>>>(Xb, Wq, in_b, qg, kg, vt);
  attn_mfma<<<dim3(32, 32), 256, 0, stream>>>(qg, kg, vt, attn);
  outproj_mfma<<<dim3(8, 64), 256, 0, stream>>>(attn, Wo, out_b, pmax);
  mlp_ctx_l1<<<32, 256, 0, stream>>>(pmax, w1, b1, h1g);
  mlp_l2<<<16, 256, 0, stream>>>(h1g, w2, b2, h2g);
  mlp_l34<<<4, 256, 0, stream>>>(h2g, w3, b3, w4, b4, (float*)d_out);
}